// Round 1
// baseline (709.589 us; speedup 1.0000x reference)
//
#include <hip/hip_runtime.h>
#include <math.h>

#define BSZ 8
#define NN 10000
#define DD 256
#define EE 160000
#define KK 5
#define BCAP 64
#define RBLK 2000

// ---------- edge_index readers (int32 vs int64 storage, device-detected) ----------
__device__ __forceinline__ int e_row(const int* ei, int f64, int e){
    return f64 ? ei[2*e] : ei[e];
}
__device__ __forceinline__ int e_col(const int* ei, int f64, int e){
    return f64 ? ei[2*(EE+e)] : ei[EE+e];
}

// ---------- bf16 helpers (manual RNE, no API dependency) ----------
__device__ __forceinline__ unsigned short f2bf(float f){
    unsigned u = __float_as_uint(f);
    u += 0x7FFFu + ((u >> 16) & 1u);
    return (unsigned short)(u >> 16);
}
__device__ __forceinline__ float bf2f(unsigned short s){
    return __uint_as_float(((unsigned)s) << 16);
}

template<typename HNT>
__device__ __forceinline__ void storev4(HNT* p, float4 v){
    if constexpr (sizeof(HNT) == 4){
        *(float4*)(void*)p = v;
    } else {
        ushort4 u; u.x = f2bf(v.x); u.y = f2bf(v.y); u.z = f2bf(v.z); u.w = f2bf(v.w);
        *(ushort4*)(void*)p = u;
    }
}
template<typename HNT>
__device__ __forceinline__ float4 loadv4(const HNT* p){
    if constexpr (sizeof(HNT) == 4){
        return *(const float4*)(const void*)p;
    } else {
        ushort4 u = *(const ushort4*)(const void*)p;
        float4 r; r.x = bf2f(u.x); r.y = bf2f(u.y); r.z = bf2f(u.z); r.w = bf2f(u.w);
        return r;
    }
}

// ---------- setup kernels ----------
__global__ void k_zero(int* fill){
    int t = blockIdx.x*blockDim.x + threadIdx.x;
    if (t < NN) fill[t] = 0;
}

__global__ void k_detect(const int* ei, int* flag){
    if (threadIdx.x == 0 && blockIdx.x == 0){
        int all0 = 1;
        for (int i = 0; i < 32; ++i) if (ei[2*i+1] != 0) all0 = 0;
        *flag = all0;   // 1 => data is int64, read low words
    }
}

__global__ void k_fill(const int* __restrict__ ei, const int* __restrict__ flag,
                       int* __restrict__ fill, int* __restrict__ bucket){
    int e = blockIdx.x*blockDim.x + threadIdx.x;
    if (e >= EE) return;
    int f = *flag;
    int r = e_row(ei, f, e);
    int pos = atomicAdd(&fill[r], 1);
    if (pos < BCAP) bucket[r*BCAP + pos] = e;
}

// One thread per row: dedup (last edge-id wins, numpy scatter semantics),
// drop diagonal edges (overwritten by 1.0) and w<=0, keep top-4 by
// (weight desc, col asc) to match lax.top_k tie-breaking.
__global__ void k_top5(const int* __restrict__ ei, const float* __restrict__ ew,
                       const int* __restrict__ flag, const int* __restrict__ fill,
                       const int* __restrict__ bucket,
                       int* __restrict__ nbr_idx, int* __restrict__ nbr_cnt){
    int r = blockIdx.x*blockDim.x + threadIdx.x;
    if (r >= NN) return;
    int f = *flag;
    int cnt = fill[r]; if (cnt > BCAP) cnt = BCAP;
    float w4[4]; int c4[4]; int mm = 0;
    for (int i = 0; i < cnt; ++i){
        int e = bucket[r*BCAP + i];
        int c = e_col(ei, f, e);
        if (c == r) continue;                    // diagonal forced to 1.0 later
        float w = ew[e];
        bool dead = false;
        for (int j = 0; j < cnt; ++j){           // duplicate (r,c): max eid wins
            if (j == i) continue;
            int e2 = bucket[r*BCAP + j];
            if (e2 > e && e_col(ei, f, e2) == c){ dead = true; break; }
        }
        if (dead) continue;
        if (!(w > 0.f)) continue;                // valid = topk_w > 0
        int p = 0;
        while (p < mm && (w4[p] > w || (w4[p] == w && c4[p] < c))) ++p;
        if (p < 4){
            int top = (mm < 4) ? mm : 3;
            for (int q = top; q > p; --q){ w4[q] = w4[q-1]; c4[q] = c4[q-1]; }
            w4[p] = w; c4[p] = c;
            if (mm < 4) ++mm;
        }
    }
    nbr_idx[r*KK + 0] = r;                        // diag (weight 1.0) always first
    for (int t = 0; t < 4; ++t) nbr_idx[r*KK + 1 + t] = (t < mm) ? c4[t] : r;
    nbr_cnt[r] = 1 + mm;
}

__global__ void k_transpose(const float* __restrict__ lin_w, float* __restrict__ linT){
    int t = blockIdx.x*blockDim.x + threadIdx.x;   // 65536
    int i = t >> 8, j = t & 255;
    linT[(size_t)j*DD + i] = lin_w[(size_t)i*DD + j];
}

// ---------- fused: attention + aggregation + linear + l2norm -> HN ----------
template<typename HNT>
__global__ __launch_bounds__(256, 2) void k_fused(
    const float* __restrict__ z1,
    const int* __restrict__ nbr_idx, const int* __restrict__ nbr_cnt,
    const float* __restrict__ sa_w, const float* __restrict__ sa_bp,
    const float* __restrict__ linT, const float* __restrict__ lin_b,
    HNT* __restrict__ HN)
{
    __shared__ float aggL[64][DD];     // 64 KB: agg tile, later reused for h tile
    __shared__ float pnorm[64][4];
    __shared__ float scaleL[64];

    const int tid  = threadIdx.x;
    const int wave = tid >> 6;
    const int lane = tid & 63;
    const int r0   = blockIdx.x * 64;

    // stage 1: each wave computes 16 rows of agg into LDS
    {
        const float4 sw = *(const float4*)&sa_w[lane*4];
        const float sab = *sa_bp;
        for (int rl = wave*16; rl < wave*16 + 16; ++rl){
            const int r = r0 + rl;
            const int b = r / NN, n = r % NN;
            const int cnt = nbr_cnt[n];
            float4 zz[5]; float at[5];
            #pragma unroll
            for (int k = 0; k < 5; ++k){
                const int idx = (k < cnt) ? nbr_idx[n*KK + k] : n;
                zz[k] = *(const float4*)&z1[((size_t)(b*NN + idx))*DD + lane*4];
                float p = zz[k].x*sw.x + zz[k].y*sw.y + zz[k].z*sw.z + zz[k].w*sw.w;
                #pragma unroll
                for (int o = 32; o > 0; o >>= 1) p += __shfl_xor(p, o, 64);
                at[k] = (k < cnt) ? (p + sab) : -1e9f;   // matches NEG_INF mask
            }
            float mx = at[0];
            #pragma unroll
            for (int k = 1; k < 5; ++k) mx = fmaxf(mx, at[k]);
            float ssum = 0.f;
            #pragma unroll
            for (int k = 0; k < 5; ++k){ at[k] = expf(at[k] - mx); ssum += at[k]; }
            const float inv = 1.f / ssum;
            float4 ag = make_float4(0.f, 0.f, 0.f, 0.f);
            #pragma unroll
            for (int k = 0; k < 5; ++k){
                const float a = at[k] * inv;
                ag.x = fmaf(a, zz[k].x, ag.x);
                ag.y = fmaf(a, zz[k].y, ag.y);
                ag.z = fmaf(a, zz[k].z, ag.z);
                ag.w = fmaf(a, zz[k].w, ag.w);
            }
            *(float4*)&aggL[rl][lane*4] = ag;
        }
    }
    __syncthreads();

    // stage 2: h = agg @ lin_w^T. Wave owns rows m0..m0+15, lane owns cols c0..c0+3.
    const int m0 = wave * 16;
    const int c0 = lane * 4;
    float acc[16][4];
    #pragma unroll
    for (int mi = 0; mi < 16; ++mi){
        acc[mi][0] = 0.f; acc[mi][1] = 0.f; acc[mi][2] = 0.f; acc[mi][3] = 0.f;
    }
    for (int j4 = 0; j4 < 64; ++j4){
        const float4 wv0 = *(const float4*)&linT[(size_t)(4*j4+0)*DD + c0];
        const float4 wv1 = *(const float4*)&linT[(size_t)(4*j4+1)*DD + c0];
        const float4 wv2 = *(const float4*)&linT[(size_t)(4*j4+2)*DD + c0];
        const float4 wv3 = *(const float4*)&linT[(size_t)(4*j4+3)*DD + c0];
        #pragma unroll
        for (int mi = 0; mi < 16; ++mi){
            const float4 a = *(const float4*)&aggL[m0+mi][4*j4];   // LDS broadcast
            acc[mi][0] = fmaf(a.x, wv0.x, acc[mi][0]);
            acc[mi][0] = fmaf(a.y, wv1.x, acc[mi][0]);
            acc[mi][0] = fmaf(a.z, wv2.x, acc[mi][0]);
            acc[mi][0] = fmaf(a.w, wv3.x, acc[mi][0]);
            acc[mi][1] = fmaf(a.x, wv0.y, acc[mi][1]);
            acc[mi][1] = fmaf(a.y, wv1.y, acc[mi][1]);
            acc[mi][1] = fmaf(a.z, wv2.y, acc[mi][1]);
            acc[mi][1] = fmaf(a.w, wv3.y, acc[mi][1]);
            acc[mi][2] = fmaf(a.x, wv0.z, acc[mi][2]);
            acc[mi][2] = fmaf(a.y, wv1.z, acc[mi][2]);
            acc[mi][2] = fmaf(a.z, wv2.z, acc[mi][2]);
            acc[mi][2] = fmaf(a.w, wv3.z, acc[mi][2]);
            acc[mi][3] = fmaf(a.x, wv0.w, acc[mi][3]);
            acc[mi][3] = fmaf(a.y, wv1.w, acc[mi][3]);
            acc[mi][3] = fmaf(a.z, wv2.w, acc[mi][3]);
            acc[mi][3] = fmaf(a.w, wv3.w, acc[mi][3]);
        }
    }
    __syncthreads();
    // write h tile back to LDS (reuse aggL)
    {
        const float4 lb = *(const float4*)&lin_b[c0];
        #pragma unroll
        for (int mi = 0; mi < 16; ++mi){
            float4 h;
            h.x = acc[mi][0] + lb.x; h.y = acc[mi][1] + lb.y;
            h.z = acc[mi][2] + lb.z; h.w = acc[mi][3] + lb.w;
            *(float4*)&aggL[m0+mi][c0] = h;
        }
    }
    __syncthreads();
    // row norms (rotated access -> conflict-free)
    {
        const int m = tid >> 2, q = tid & 3;
        float pp = 0.f;
        for (int t = 0; t < 64; ++t){
            const float v = aggL[m][q*64 + ((t + tid) & 63)];
            pp = fmaf(v, v, pp);
        }
        pnorm[m][q] = pp;
    }
    __syncthreads();
    if (tid < 64){
        const float s = pnorm[tid][0] + pnorm[tid][1] + pnorm[tid][2] + pnorm[tid][3];
        scaleL[tid] = 1.f / fmaxf(sqrtf(s), 1e-12f);
    }
    __syncthreads();
    #pragma unroll
    for (int mi = 0; mi < 16; ++mi){
        const float sc = scaleL[m0+mi];
        float4 v = *(const float4*)&aggL[m0+mi][c0];
        v.x *= sc; v.y *= sc; v.z *= sc; v.w *= sc;
        storev4(&HN[((size_t)(r0 + m0 + mi))*DD + c0], v);
    }
}

// ---------- loss/acc reduction ----------
template<typename HNT>
__global__ __launch_bounds__(256) void k_reduce(
    const float* __restrict__ z2, const HNT* __restrict__ HN,
    double* __restrict__ loss_part, long long* __restrict__ cnt_part)
{
    const int tid = threadIdx.x;
    const int wave = tid >> 6, lane = tid & 63;
    const int gw = blockIdx.x*4 + wave;
    double lacc = 0.0;
    int cacc = 0;
    for (int r = gw; r < BSZ*NN; r += RBLK*4){
        const int b = r / NN, n = r % NN;
        const int pb = (5*b + 3) & 7;                 // fixed bijection on batch
        const int qn = (n * 7919 + 1234) % NN;        // fixed bijection on nodes
        const float4 zv = *(const float4*)&z2[((size_t)r)*DD + lane*4];
        const float4 hs = loadv4(&HN[((size_t)r)*DD + lane*4]);
        const float4 hf = loadv4(&HN[((size_t)(pb*NN + qn))*DD + lane*4]);
        float pz = zv.x*zv.x + zv.y*zv.y + zv.z*zv.z + zv.w*zv.w;
        float pr = zv.x*hs.x + zv.y*hs.y + zv.z*hs.z + zv.w*hs.w;
        float pf = zv.x*hf.x + zv.y*hf.y + zv.z*hf.z + zv.w*hf.w;
        #pragma unroll
        for (int o = 32; o > 0; o >>= 1){
            pz += __shfl_xor(pz, o, 64);
            pr += __shfl_xor(pr, o, 64);
            pf += __shfl_xor(pf, o, 64);
        }
        if (lane == 0){
            const float dn = fmaxf(sqrtf(pz), 1e-12f);
            const float x = pr / dn, y = pf / dn;
            const float lr = fmaxf(x, 0.f) - x + log1pf(expf(-fabsf(x)));  // lbl=1
            const float lf = fmaxf(y, 0.f)     + log1pf(expf(-fabsf(y)));  // lbl=0
            lacc += (double)(lr + lf);
            cacc += (x > 0.f ? 1 : 0) + (y > 0.f ? 0 : 1);
        }
    }
    __shared__ double sl[4];
    __shared__ int scn[4];
    if (lane == 0){ sl[wave] = lacc; scn[wave] = cacc; }
    __syncthreads();
    if (tid == 0){
        loss_part[blockIdx.x] = sl[0]+sl[1]+sl[2]+sl[3];
        cnt_part[blockIdx.x]  = (long long)scn[0] + scn[1] + scn[2] + scn[3];
    }
}

__global__ void k_final(const double* __restrict__ loss_part,
                        const long long* __restrict__ cnt_part,
                        float* __restrict__ out){
    __shared__ double sl[256];
    __shared__ long long sc[256];
    double l = 0.0; long long c = 0;
    for (int i = threadIdx.x; i < RBLK; i += 256){ l += loss_part[i]; c += cnt_part[i]; }
    sl[threadIdx.x] = l; sc[threadIdx.x] = c;
    __syncthreads();
    for (int s = 128; s > 0; s >>= 1){
        if (threadIdx.x < s){
            sl[threadIdx.x] += sl[threadIdx.x + s];
            sc[threadIdx.x] += sc[threadIdx.x + s];
        }
        __syncthreads();
    }
    if (threadIdx.x == 0){
        const double denom = 2.0 * BSZ * NN;   // 160000
        out[0] = (float)(sl[0] / denom);
        out[1] = (float)((double)sc[0] / denom);
    }
}

// ---------- host ----------
extern "C" void kernel_launch(void* const* d_in, const int* in_sizes, int n_in,
                              void* d_out, int out_size, void* d_ws, size_t ws_size,
                              hipStream_t stream)
{
    (void)in_sizes; (void)n_in; (void)out_size;
    const float* z1    = (const float*)d_in[0];
    const float* z2    = (const float*)d_in[1];
    const int*   ei    = (const int*)d_in[2];
    const float* ew    = (const float*)d_in[3];
    const float* sa_w  = (const float*)d_in[4];
    const float* sa_b  = (const float*)d_in[5];
    const float* lin_w = (const float*)d_in[6];
    const float* lin_b = (const float*)d_in[7];
    float* out = (float*)d_out;

    char* ws = (char*)d_ws;
    size_t off = 0;
    auto take = [&](size_t bytes) -> char* {
        char* p = ws + off;
        off = (off + bytes + 255) & ~(size_t)255;
        return p;
    };
    int*       flag      = (int*)take(4);
    int*       fill      = (int*)take((size_t)NN*4);
    int*       bucket    = (int*)take((size_t)NN*BCAP*4);
    int*       nbr_idx   = (int*)take((size_t)NN*KK*4);
    int*       nbr_cnt   = (int*)take((size_t)NN*4);
    float*     linT      = (float*)take((size_t)DD*DD*4);
    double*    loss_part = (double*)take((size_t)RBLK*8);
    long long* cnt_part  = (long long*)take((size_t)RBLK*8);
    const size_t hn_off  = off;
    const size_t hn_f32_bytes = (size_t)BSZ*NN*DD*4;
    const bool f32hn = (ws_size >= hn_off + hn_f32_bytes);
    void* HN = ws + hn_off;

    k_zero<<<(NN+255)/256, 256, 0, stream>>>(fill);
    k_detect<<<1, 64, 0, stream>>>(ei, flag);
    k_fill<<<(EE+255)/256, 256, 0, stream>>>(ei, flag, fill, bucket);
    k_top5<<<(NN+255)/256, 256, 0, stream>>>(ei, ew, flag, fill, bucket, nbr_idx, nbr_cnt);
    k_transpose<<<(DD*DD)/256, 256, 0, stream>>>(lin_w, linT);

    if (f32hn){
        k_fused<float><<<(BSZ*NN)/64, 256, 0, stream>>>(
            z1, nbr_idx, nbr_cnt, sa_w, sa_b, linT, lin_b, (float*)HN);
        k_reduce<float><<<RBLK, 256, 0, stream>>>(
            z2, (const float*)HN, loss_part, cnt_part);
    } else {
        k_fused<unsigned short><<<(BSZ*NN)/64, 256, 0, stream>>>(
            z1, nbr_idx, nbr_cnt, sa_w, sa_b, linT, lin_b, (unsigned short*)HN);
        k_reduce<unsigned short><<<RBLK, 256, 0, stream>>>(
            z2, (const unsigned short*)HN, loss_part, cnt_part);
    }
    k_final<<<1, 256, 0, stream>>>(loss_part, cnt_part, out);
}

// Round 2
// 346.900 us; speedup vs baseline: 2.0455x; 2.0455x over previous
//
#include <hip/hip_runtime.h>
#include <math.h>

#define BSZ 8
#define NN 10000
#define DD 256
#define EE 160000
#define KK 5
#define BCAP 64
#define RBLK 2000

// ---------- edge_index readers (int32 vs int64 storage, device-detected) ----------
__device__ __forceinline__ int e_row(const int* ei, int f64, int e){
    return f64 ? ei[2*e] : ei[e];
}
__device__ __forceinline__ int e_col(const int* ei, int f64, int e){
    return f64 ? ei[2*(EE+e)] : ei[EE+e];
}

// ---------- bf16 helpers (manual RNE, no API dependency) ----------
__device__ __forceinline__ unsigned short f2bf(float f){
    unsigned u = __float_as_uint(f);
    u += 0x7FFFu + ((u >> 16) & 1u);
    return (unsigned short)(u >> 16);
}
__device__ __forceinline__ float bf2f(unsigned short s){
    return __uint_as_float(((unsigned)s) << 16);
}

template<typename HNT>
__device__ __forceinline__ void storev4(HNT* p, float4 v){
    if constexpr (sizeof(HNT) == 4){
        *(float4*)(void*)p = v;
    } else {
        ushort4 u; u.x = f2bf(v.x); u.y = f2bf(v.y); u.z = f2bf(v.z); u.w = f2bf(v.w);
        *(ushort4*)(void*)p = u;
    }
}
template<typename HNT>
__device__ __forceinline__ float4 loadv4(const HNT* p){
    if constexpr (sizeof(HNT) == 4){
        return *(const float4*)(const void*)p;
    } else {
        ushort4 u = *(const ushort4*)(const void*)p;
        float4 r; r.x = bf2f(u.x); r.y = bf2f(u.y); r.z = bf2f(u.z); r.w = bf2f(u.w);
        return r;
    }
}

// ---------- setup kernels ----------
__global__ void k_zero(int* fill){
    int t = blockIdx.x*blockDim.x + threadIdx.x;
    if (t < NN) fill[t] = 0;
}

__global__ void k_detect(const int* ei, int* flag){
    if (threadIdx.x == 0 && blockIdx.x == 0){
        int all0 = 1;
        for (int i = 0; i < 32; ++i) if (ei[2*i+1] != 0) all0 = 0;
        *flag = all0;   // 1 => data is int64, read low words
    }
}

// Stage (col, weight, eid) per row so top-k never re-reads edge_index.
__global__ void k_fill(const int* __restrict__ ei, const float* __restrict__ ew,
                       const int* __restrict__ flag,
                       int* __restrict__ fill, int* __restrict__ bc,
                       float* __restrict__ bw, int* __restrict__ be){
    int e = blockIdx.x*blockDim.x + threadIdx.x;
    if (e >= EE) return;
    int f = *flag;
    int r = e_row(ei, f, e);
    int c = e_col(ei, f, e);
    int pos = atomicAdd(&fill[r], 1);
    if (pos < BCAP){
        bc[r*BCAP + pos] = c;
        bw[r*BCAP + pos] = ew[e];
        be[r*BCAP + pos] = e;
    }
}

// One WAVE per row. Lane i owns bucket entry i (registers only).
// Dedup: numpy last-write-wins => max eid per (r,c) survives with its weight.
// Drop diagonal edges (overwritten by 1.0) and w<=0 (valid = topk_w > 0).
// Rank alive entries by (w desc, c asc) to match lax.top_k tie-breaking;
// ranks are unique (no two alive entries share (w,c) after dedup).
__global__ __launch_bounds__(256) void k_top5(
    const int* __restrict__ fill, const int* __restrict__ bc,
    const float* __restrict__ bw, const int* __restrict__ be,
    int* __restrict__ nbr_idx, int* __restrict__ nbr_cnt)
{
    const int wave = threadIdx.x >> 6, lane = threadIdx.x & 63;
    const int r = blockIdx.x*4 + wave;
    if (r >= NN) return;
    int cnt = fill[r]; if (cnt > BCAP) cnt = BCAP;

    int c = -1, e = -1; float w = 0.f;
    if (lane < cnt){
        c = bc[r*BCAP + lane];
        w = bw[r*BCAP + lane];
        e = be[r*BCAP + lane];
    }
    bool alive = (lane < cnt) && (c != r) && (w > 0.f);

    // dedup: killed if any entry with same col has larger eid
    for (int j = 0; j < cnt; ++j){
        const int cj = __shfl(c, j, 64);
        const int ej = __shfl(e, j, 64);
        if (cj == c && ej > e) alive = false;
    }
    // rank among alive entries
    int rank = 0;
    const int av = alive ? 1 : 0;
    for (int j = 0; j < cnt; ++j){
        const int   aj = __shfl(av, j, 64);
        const float wj = __shfl(w,  j, 64);
        const int   cj = __shfl(c,  j, 64);
        if (aj && (wj > w || (wj == w && cj < c))) ++rank;
    }
    // gather: lane t (1..4) collects the col of the alive entry with rank t-1
    const int want = lane - 1;          // lane 0 wants rank -1 -> stays r (diag)
    int val = r;
    for (int j = 0; j < cnt; ++j){
        const int aj = __shfl(av,   j, 64);
        const int rj = __shfl(rank, j, 64);
        const int cj = __shfl(c,    j, 64);
        if (aj && rj == want && rj < 4) val = cj;
    }
    if (lane < KK) nbr_idx[r*KK + lane] = val;
    if (lane == 0){
        const int na = __popcll(__ballot(alive));
        nbr_cnt[r] = 1 + (na < 4 ? na : 4);
    }
}

__global__ void k_transpose(const float* __restrict__ lin_w, float* __restrict__ linT){
    int t = blockIdx.x*blockDim.x + threadIdx.x;   // 65536
    int i = t >> 8, j = t & 255;
    linT[(size_t)j*DD + i] = lin_w[(size_t)i*DD + j];
}

// ---------- fused: attention + aggregation + linear + l2norm -> HN ----------
template<typename HNT>
__global__ __launch_bounds__(256, 2) void k_fused(
    const float* __restrict__ z1,
    const int* __restrict__ nbr_idx, const int* __restrict__ nbr_cnt,
    const float* __restrict__ sa_w, const float* __restrict__ sa_bp,
    const float* __restrict__ linT, const float* __restrict__ lin_b,
    HNT* __restrict__ HN)
{
    __shared__ float aggL[64][DD];     // 64 KB: agg tile, later reused for h tile
    __shared__ float pnorm[64][4];
    __shared__ float scaleL[64];

    const int tid  = threadIdx.x;
    const int wave = tid >> 6;
    const int lane = tid & 63;
    const int r0   = blockIdx.x * 64;

    // stage 1: each wave computes 16 rows of agg into LDS
    {
        const float4 sw = *(const float4*)&sa_w[lane*4];
        const float sab = *sa_bp;
        for (int rl = wave*16; rl < wave*16 + 16; ++rl){
            const int r = r0 + rl;
            const int b = r / NN, n = r % NN;
            const int cnt = nbr_cnt[n];
            float4 zz[5]; float at[5];
            #pragma unroll
            for (int k = 0; k < 5; ++k){
                const int idx = (k < cnt) ? nbr_idx[n*KK + k] : n;
                zz[k] = *(const float4*)&z1[((size_t)(b*NN + idx))*DD + lane*4];
                float p = zz[k].x*sw.x + zz[k].y*sw.y + zz[k].z*sw.z + zz[k].w*sw.w;
                #pragma unroll
                for (int o = 32; o > 0; o >>= 1) p += __shfl_xor(p, o, 64);
                at[k] = (k < cnt) ? (p + sab) : -1e9f;   // matches NEG_INF mask
            }
            float mx = at[0];
            #pragma unroll
            for (int k = 1; k < 5; ++k) mx = fmaxf(mx, at[k]);
            float ssum = 0.f;
            #pragma unroll
            for (int k = 0; k < 5; ++k){ at[k] = expf(at[k] - mx); ssum += at[k]; }
            const float inv = 1.f / ssum;
            float4 ag = make_float4(0.f, 0.f, 0.f, 0.f);
            #pragma unroll
            for (int k = 0; k < 5; ++k){
                const float a = at[k] * inv;
                ag.x = fmaf(a, zz[k].x, ag.x);
                ag.y = fmaf(a, zz[k].y, ag.y);
                ag.z = fmaf(a, zz[k].z, ag.z);
                ag.w = fmaf(a, zz[k].w, ag.w);
            }
            *(float4*)&aggL[rl][lane*4] = ag;
        }
    }
    __syncthreads();

    // stage 2: h = agg @ lin_w^T. Wave owns rows m0..m0+15, lane owns cols c0..c0+3.
    const int m0 = wave * 16;
    const int c0 = lane * 4;
    float acc[16][4];
    #pragma unroll
    for (int mi = 0; mi < 16; ++mi){
        acc[mi][0] = 0.f; acc[mi][1] = 0.f; acc[mi][2] = 0.f; acc[mi][3] = 0.f;
    }
    for (int j4 = 0; j4 < 64; ++j4){
        const float4 wv0 = *(const float4*)&linT[(size_t)(4*j4+0)*DD + c0];
        const float4 wv1 = *(const float4*)&linT[(size_t)(4*j4+1)*DD + c0];
        const float4 wv2 = *(const float4*)&linT[(size_t)(4*j4+2)*DD + c0];
        const float4 wv3 = *(const float4*)&linT[(size_t)(4*j4+3)*DD + c0];
        #pragma unroll
        for (int mi = 0; mi < 16; ++mi){
            const float4 a = *(const float4*)&aggL[m0+mi][4*j4];   // LDS broadcast
            acc[mi][0] = fmaf(a.x, wv0.x, acc[mi][0]);
            acc[mi][0] = fmaf(a.y, wv1.x, acc[mi][0]);
            acc[mi][0] = fmaf(a.z, wv2.x, acc[mi][0]);
            acc[mi][0] = fmaf(a.w, wv3.x, acc[mi][0]);
            acc[mi][1] = fmaf(a.x, wv0.y, acc[mi][1]);
            acc[mi][1] = fmaf(a.y, wv1.y, acc[mi][1]);
            acc[mi][1] = fmaf(a.z, wv2.y, acc[mi][1]);
            acc[mi][1] = fmaf(a.w, wv3.y, acc[mi][1]);
            acc[mi][2] = fmaf(a.x, wv0.z, acc[mi][2]);
            acc[mi][2] = fmaf(a.y, wv1.z, acc[mi][2]);
            acc[mi][2] = fmaf(a.z, wv2.z, acc[mi][2]);
            acc[mi][2] = fmaf(a.w, wv3.z, acc[mi][2]);
            acc[mi][3] = fmaf(a.x, wv0.w, acc[mi][3]);
            acc[mi][3] = fmaf(a.y, wv1.w, acc[mi][3]);
            acc[mi][3] = fmaf(a.z, wv2.w, acc[mi][3]);
            acc[mi][3] = fmaf(a.w, wv3.w, acc[mi][3]);
        }
    }
    __syncthreads();
    // write h tile back to LDS (reuse aggL)
    {
        const float4 lb = *(const float4*)&lin_b[c0];
        #pragma unroll
        for (int mi = 0; mi < 16; ++mi){
            float4 h;
            h.x = acc[mi][0] + lb.x; h.y = acc[mi][1] + lb.y;
            h.z = acc[mi][2] + lb.z; h.w = acc[mi][3] + lb.w;
            *(float4*)&aggL[m0+mi][c0] = h;
        }
    }
    __syncthreads();
    // row norms (rotated access -> conflict-free)
    {
        const int m = tid >> 2, q = tid & 3;
        float pp = 0.f;
        for (int t = 0; t < 64; ++t){
            const float v = aggL[m][q*64 + ((t + tid) & 63)];
            pp = fmaf(v, v, pp);
        }
        pnorm[m][q] = pp;
    }
    __syncthreads();
    if (tid < 64){
        const float s = pnorm[tid][0] + pnorm[tid][1] + pnorm[tid][2] + pnorm[tid][3];
        scaleL[tid] = 1.f / fmaxf(sqrtf(s), 1e-12f);
    }
    __syncthreads();
    #pragma unroll
    for (int mi = 0; mi < 16; ++mi){
        const float sc = scaleL[m0+mi];
        float4 v = *(const float4*)&aggL[m0+mi][c0];
        v.x *= sc; v.y *= sc; v.z *= sc; v.w *= sc;
        storev4(&HN[((size_t)(r0 + m0 + mi))*DD + c0], v);
    }
}

// ---------- loss/acc reduction ----------
template<typename HNT>
__global__ __launch_bounds__(256) void k_reduce(
    const float* __restrict__ z2, const HNT* __restrict__ HN,
    double* __restrict__ loss_part, long long* __restrict__ cnt_part)
{
    const int tid = threadIdx.x;
    const int wave = tid >> 6, lane = tid & 63;
    const int gw = blockIdx.x*4 + wave;
    double lacc = 0.0;
    int cacc = 0;
    for (int r = gw; r < BSZ*NN; r += RBLK*4){
        const int b = r / NN, n = r % NN;
        const int pb = (5*b + 3) & 7;                 // fixed bijection on batch
        const int qn = (n * 7919 + 1234) % NN;        // fixed bijection on nodes
        const float4 zv = *(const float4*)&z2[((size_t)r)*DD + lane*4];
        const float4 hs = loadv4(&HN[((size_t)r)*DD + lane*4]);
        const float4 hf = loadv4(&HN[((size_t)(pb*NN + qn))*DD + lane*4]);
        float pz = zv.x*zv.x + zv.y*zv.y + zv.z*zv.z + zv.w*zv.w;
        float pr = zv.x*hs.x + zv.y*hs.y + zv.z*hs.z + zv.w*hs.w;
        float pf = zv.x*hf.x + zv.y*hf.y + zv.z*hf.z + zv.w*hf.w;
        #pragma unroll
        for (int o = 32; o > 0; o >>= 1){
            pz += __shfl_xor(pz, o, 64);
            pr += __shfl_xor(pr, o, 64);
            pf += __shfl_xor(pf, o, 64);
        }
        if (lane == 0){
            const float dn = fmaxf(sqrtf(pz), 1e-12f);
            const float x = pr / dn, y = pf / dn;
            const float lr = fmaxf(x, 0.f) - x + log1pf(expf(-fabsf(x)));  // lbl=1
            const float lf = fmaxf(y, 0.f)     + log1pf(expf(-fabsf(y)));  // lbl=0
            lacc += (double)(lr + lf);
            cacc += (x > 0.f ? 1 : 0) + (y > 0.f ? 0 : 1);
        }
    }
    __shared__ double sl[4];
    __shared__ int scn[4];
    if (lane == 0){ sl[wave] = lacc; scn[wave] = cacc; }
    __syncthreads();
    if (tid == 0){
        loss_part[blockIdx.x] = sl[0]+sl[1]+sl[2]+sl[3];
        cnt_part[blockIdx.x]  = (long long)scn[0] + scn[1] + scn[2] + scn[3];
    }
}

__global__ void k_final(const double* __restrict__ loss_part,
                        const long long* __restrict__ cnt_part,
                        float* __restrict__ out){
    __shared__ double sl[256];
    __shared__ long long sc[256];
    double l = 0.0; long long c = 0;
    for (int i = threadIdx.x; i < RBLK; i += 256){ l += loss_part[i]; c += cnt_part[i]; }
    sl[threadIdx.x] = l; sc[threadIdx.x] = c;
    __syncthreads();
    for (int s = 128; s > 0; s >>= 1){
        if (threadIdx.x < s){
            sl[threadIdx.x] += sl[threadIdx.x + s];
            sc[threadIdx.x] += sc[threadIdx.x + s];
        }
        __syncthreads();
    }
    if (threadIdx.x == 0){
        const double denom = 2.0 * BSZ * NN;   // 160000
        out[0] = (float)(sl[0] / denom);
        out[1] = (float)((double)sc[0] / denom);
    }
}

// ---------- host ----------
extern "C" void kernel_launch(void* const* d_in, const int* in_sizes, int n_in,
                              void* d_out, int out_size, void* d_ws, size_t ws_size,
                              hipStream_t stream)
{
    (void)in_sizes; (void)n_in; (void)out_size;
    const float* z1    = (const float*)d_in[0];
    const float* z2    = (const float*)d_in[1];
    const int*   ei    = (const int*)d_in[2];
    const float* ew    = (const float*)d_in[3];
    const float* sa_w  = (const float*)d_in[4];
    const float* sa_b  = (const float*)d_in[5];
    const float* lin_w = (const float*)d_in[6];
    const float* lin_b = (const float*)d_in[7];
    float* out = (float*)d_out;

    char* ws = (char*)d_ws;
    size_t off = 0;
    auto take = [&](size_t bytes) -> char* {
        char* p = ws + off;
        off = (off + bytes + 255) & ~(size_t)255;
        return p;
    };
    int*       flag      = (int*)take(4);
    int*       fill      = (int*)take((size_t)NN*4);
    int*       bc        = (int*)take((size_t)NN*BCAP*4);
    float*     bw        = (float*)take((size_t)NN*BCAP*4);
    int*       be        = (int*)take((size_t)NN*BCAP*4);
    int*       nbr_idx   = (int*)take((size_t)NN*KK*4);
    int*       nbr_cnt   = (int*)take((size_t)NN*4);
    float*     linT      = (float*)take((size_t)DD*DD*4);
    double*    loss_part = (double*)take((size_t)RBLK*8);
    long long* cnt_part  = (long long*)take((size_t)RBLK*8);
    const size_t hn_off  = off;
    const size_t hn_f32_bytes = (size_t)BSZ*NN*DD*4;
    const bool f32hn = (ws_size >= hn_off + hn_f32_bytes);
    void* HN = ws + hn_off;

    k_zero<<<(NN+255)/256, 256, 0, stream>>>(fill);
    k_detect<<<1, 64, 0, stream>>>(ei, flag);
    k_fill<<<(EE+255)/256, 256, 0, stream>>>(ei, ew, flag, fill, bc, bw, be);
    k_top5<<<(NN+3)/4, 256, 0, stream>>>(fill, bc, bw, be, nbr_idx, nbr_cnt);
    k_transpose<<<(DD*DD)/256, 256, 0, stream>>>(lin_w, linT);

    if (f32hn){
        k_fused<float><<<(BSZ*NN)/64, 256, 0, stream>>>(
            z1, nbr_idx, nbr_cnt, sa_w, sa_b, linT, lin_b, (float*)HN);
        k_reduce<float><<<RBLK, 256, 0, stream>>>(
            z2, (const float*)HN, loss_part, cnt_part);
    } else {
        k_fused<unsigned short><<<(BSZ*NN)/64, 256, 0, stream>>>(
            z1, nbr_idx, nbr_cnt, sa_w, sa_b, linT, lin_b, (unsigned short*)HN);
        k_reduce<unsigned short><<<RBLK, 256, 0, stream>>>(
            z2, (const unsigned short*)HN, loss_part, cnt_part);
    }
    k_final<<<1, 256, 0, stream>>>(loss_part, cnt_part, out);
}

// Round 3
// 220.280 us; speedup vs baseline: 3.2213x; 1.5748x over previous
//
#include <hip/hip_runtime.h>
#include <math.h>

#define BSZ 8
#define NN 10000
#define DD 256
#define EE 160000
#define KK 5
#define BCAP 64
#define RBLK 2000
#define NROW (BSZ*NN)

typedef __attribute__((ext_vector_type(8))) short short8;
typedef __attribute__((ext_vector_type(4))) float f32x4;

// ---------- edge_index readers (int32 vs int64 storage, device-detected) ----------
__device__ __forceinline__ int e_row(const int* ei, int f64, int e){
    return f64 ? ei[2*e] : ei[e];
}
__device__ __forceinline__ int e_col(const int* ei, int f64, int e){
    return f64 ? ei[2*(EE+e)] : ei[EE+e];
}

// ---------- bf16 helpers (manual RNE) ----------
__device__ __forceinline__ unsigned short f2bf(float f){
    unsigned u = __float_as_uint(f);
    u += 0x7FFFu + ((u >> 16) & 1u);
    return (unsigned short)(u >> 16);
}
__device__ __forceinline__ float bf2f(unsigned short s){
    return __uint_as_float(((unsigned)s) << 16);
}

// ---------- setup kernels ----------
__global__ void k_zero(int* fill){
    int t = blockIdx.x*blockDim.x + threadIdx.x;
    if (t < NN) fill[t] = 0;
}

__global__ void k_detect(const int* ei, int* flag){
    if (threadIdx.x == 0 && blockIdx.x == 0){
        int all0 = 1;
        for (int i = 0; i < 32; ++i) if (ei[2*i+1] != 0) all0 = 0;
        *flag = all0;   // 1 => data is int64, read low words
    }
}

// Stage (col, weight, eid) per row so top-k never re-reads edge_index.
__global__ void k_fill(const int* __restrict__ ei, const float* __restrict__ ew,
                       const int* __restrict__ flag,
                       int* __restrict__ fill, int* __restrict__ bc,
                       float* __restrict__ bw, int* __restrict__ be){
    int e = blockIdx.x*blockDim.x + threadIdx.x;
    if (e >= EE) return;
    int f = *flag;
    int r = e_row(ei, f, e);
    int c = e_col(ei, f, e);
    int pos = atomicAdd(&fill[r], 1);
    if (pos < BCAP){
        bc[r*BCAP + pos] = c;
        bw[r*BCAP + pos] = ew[e];
        be[r*BCAP + pos] = e;
    }
}

// One WAVE per row: dedup (max eid wins per (r,c) = numpy last-write-wins),
// drop diagonal edges and w<=0, rank by (w desc, c asc) = lax.top_k order.
__global__ __launch_bounds__(256) void k_top5(
    const int* __restrict__ fill, const int* __restrict__ bc,
    const float* __restrict__ bw, const int* __restrict__ be,
    int* __restrict__ nbr_idx, int* __restrict__ nbr_cnt)
{
    const int wave = threadIdx.x >> 6, lane = threadIdx.x & 63;
    const int r = blockIdx.x*4 + wave;
    if (r >= NN) return;
    int cnt = fill[r]; if (cnt > BCAP) cnt = BCAP;

    int c = -1, e = -1; float w = 0.f;
    if (lane < cnt){
        c = bc[r*BCAP + lane];
        w = bw[r*BCAP + lane];
        e = be[r*BCAP + lane];
    }
    bool alive = (lane < cnt) && (c != r) && (w > 0.f);

    for (int j = 0; j < cnt; ++j){
        const int cj = __shfl(c, j, 64);
        const int ej = __shfl(e, j, 64);
        if (cj == c && ej > e) alive = false;
    }
    int rank = 0;
    const int av = alive ? 1 : 0;
    for (int j = 0; j < cnt; ++j){
        const int   aj = __shfl(av, j, 64);
        const float wj = __shfl(w,  j, 64);
        const int   cj = __shfl(c,  j, 64);
        if (aj && (wj > w || (wj == w && cj < c))) ++rank;
    }
    const int want = lane - 1;
    int val = r;
    for (int j = 0; j < cnt; ++j){
        const int aj = __shfl(av,   j, 64);
        const int rj = __shfl(rank, j, 64);
        const int cj = __shfl(c,    j, 64);
        if (aj && rj == want && rj < 4) val = cj;
    }
    if (lane < KK) nbr_idx[r*KK + lane] = val;
    if (lane == 0){
        const int na = __popcll(__ballot(alive));
        nbr_cnt[r] = 1 + (na < 4 ? na : 4);
    }
}

// Pack lin_w into MFMA B-fragment order (bf16).
// Bpack[nt][ks][lane][i] = bf16(lin_w[n][k]), n = nt*16+(lane&15),
// k = ks*32+(lane>>4)*8+i  (B: col=lane&15, k=(lane>>4)*8+i per 16x16x32 layout)
__global__ void k_pack(const float* __restrict__ lin_w, unsigned short* __restrict__ Bpack){
    int t = blockIdx.x*256 + threadIdx.x;   // 8192 = 16nt * 8ks * 64lane
    int l = t & 63, ks = (t>>6)&7, nt = t>>9;
    int n  = nt*16 + (l&15);
    int k0 = ks*32 + (l>>4)*8;
    const float* src = &lin_w[(size_t)n*DD + k0];
    ushort4 o0, o1;
    o0.x=f2bf(src[0]); o0.y=f2bf(src[1]); o0.z=f2bf(src[2]); o0.w=f2bf(src[3]);
    o1.x=f2bf(src[4]); o1.y=f2bf(src[5]); o1.z=f2bf(src[6]); o1.w=f2bf(src[7]);
    *(ushort4*)&Bpack[(size_t)t*8]     = o0;
    *(ushort4*)&Bpack[(size_t)t*8 + 4] = o1;
}

// One pass over z1: S[r] = z1[r]·sa_w + sa_b, and (optionally) z1b = bf16(z1).
template<bool ZB>
__global__ __launch_bounds__(256) void k_prep(const float* __restrict__ z1,
    const float* __restrict__ sa_w, const float* __restrict__ sa_bp,
    unsigned short* __restrict__ z1b, float* __restrict__ S)
{
    const int wave = threadIdx.x >> 6, lane = threadIdx.x & 63;
    const int wg = blockIdx.x*4 + wave;          // 0..4999
    const float4 sw = *(const float4*)&sa_w[lane*4];
    const float sab = *sa_bp;
    for (int r = wg*16; r < wg*16 + 16; ++r){
        const float4 v = *(const float4*)&z1[(size_t)r*DD + lane*4];
        if constexpr (ZB){
            ushort4 u;
            u.x = f2bf(v.x); u.y = f2bf(v.y); u.z = f2bf(v.z); u.w = f2bf(v.w);
            *(ushort4*)&z1b[(size_t)r*DD + lane*4] = u;
        }
        float p = v.x*sw.x + v.y*sw.y + v.z*sw.z + v.w*sw.w;
        #pragma unroll
        for (int o = 32; o > 0; o >>= 1) p += __shfl_xor(p, o, 64);
        if (lane == 0) S[r] = p + sab;
    }
}

// Per-(b,n) softmax over the 5 gathered S values.
__global__ void k_attn(const int* __restrict__ nbr_idx, const int* __restrict__ nbr_cnt,
                       const float* __restrict__ S, float* __restrict__ attw){
    int t = blockIdx.x*256 + threadIdx.x;
    if (t >= NROW) return;
    int b = t / NN, n = t % NN;
    int cnt = nbr_cnt[n];
    float lg[KK];
    #pragma unroll
    for (int k = 0; k < KK; ++k){
        int idx = nbr_idx[n*KK + k];
        lg[k] = (k < cnt) ? S[b*NN + idx] : -1e9f;
    }
    float m = lg[0];
    #pragma unroll
    for (int k = 1; k < KK; ++k) m = fmaxf(m, lg[k]);
    float s = 0.f;
    #pragma unroll
    for (int k = 0; k < KK; ++k){ lg[k] = expf(lg[k] - m); s += lg[k]; }
    const float inv = 1.f/s;
    #pragma unroll
    for (int k = 0; k < KK; ++k) attw[(size_t)t*KK + k] = lg[k]*inv;
}

// ---------- fused: gather-agg (bf16 LDS) + MFMA GEMM + bias + l2norm -> bf16 HN
// Wave-self-contained: wave w computes rows m0=w*16..+16; no __syncthreads.
template<bool ZB>
__global__ __launch_bounds__(256, 4) void k_fused(
    const float* __restrict__ z1, const unsigned short* __restrict__ z1b,
    const int* __restrict__ nbr_idx, const float* __restrict__ attw,
    const unsigned short* __restrict__ Bpack, const float* __restrict__ lin_b,
    unsigned short* __restrict__ HN)
{
    __shared__ __align__(16) unsigned short aggL[4][16][264];  // +8 pad: row stride 528B

    const int tid = threadIdx.x, wave = tid >> 6, lane = tid & 63;
    const int r0 = blockIdx.x*64, m0 = wave*16;

    // stage 1: gather + weighted sum -> bf16 LDS tile (wave-local rows)
    for (int rl = 0; rl < 16; ++rl){
        const int r = r0 + m0 + rl;
        const int b = r / NN, n = r % NN;
        float4 ag = make_float4(0.f,0.f,0.f,0.f);
        #pragma unroll
        for (int k = 0; k < KK; ++k){
            const int   idx = nbr_idx[n*KK + k];
            const float w   = attw[(size_t)r*KK + k];
            const size_t gr = (size_t)(b*NN + idx)*DD + lane*4;
            float4 v;
            if constexpr (ZB){
                ushort4 u = *(const ushort4*)&z1b[gr];
                v = make_float4(bf2f(u.x), bf2f(u.y), bf2f(u.z), bf2f(u.w));
            } else {
                v = *(const float4*)&z1[gr];
            }
            ag.x = fmaf(w, v.x, ag.x);
            ag.y = fmaf(w, v.y, ag.y);
            ag.z = fmaf(w, v.z, ag.z);
            ag.w = fmaf(w, v.w, ag.w);
        }
        ushort4 o;
        o.x = f2bf(ag.x); o.y = f2bf(ag.y); o.z = f2bf(ag.z); o.w = f2bf(ag.w);
        *(ushort4*)&aggL[wave][rl][lane*4] = o;
    }

    // stage 2: h = agg @ lin_w^T via mfma_f32_16x16x32_bf16
    // A: row=lane&15, k=(lane>>4)*8+i ; B from Bpack ; C/D: col=lane&15, row=(lane>>4)*4+reg
    const unsigned short* aRow = &aggL[wave][lane & 15][(lane >> 4) * 8];
    const short8* bPtr = (const short8*)Bpack + lane;
    f32x4 acc[16];
    #pragma unroll
    for (int nt = 0; nt < 16; ++nt) acc[nt] = (f32x4){0.f,0.f,0.f,0.f};
    for (int ks = 0; ks < 8; ++ks){
        const short8 a = *(const short8*)(aRow + ks*32);
        #pragma unroll
        for (int nt = 0; nt < 16; ++nt){
            const short8 bb = bPtr[(nt*8 + ks)*64];
            acc[nt] = __builtin_amdgcn_mfma_f32_16x16x32_bf16(a, bb, acc[nt], 0, 0, 0);
        }
    }

    // epilogue: + bias, row l2norm (shfl over lane&15 group), bf16 store
    float sq[4] = {0.f,0.f,0.f,0.f};
    #pragma unroll
    for (int nt = 0; nt < 16; ++nt){
        const float bv = lin_b[nt*16 + (lane & 15)];
        #pragma unroll
        for (int reg = 0; reg < 4; ++reg){
            float h = acc[nt][reg] + bv;
            acc[nt][reg] = h;
            sq[reg] = fmaf(h, h, sq[reg]);
        }
    }
    #pragma unroll
    for (int off = 1; off < 16; off <<= 1){
        #pragma unroll
        for (int reg = 0; reg < 4; ++reg) sq[reg] += __shfl_xor(sq[reg], off, 64);
    }
    float sc[4];
    #pragma unroll
    for (int reg = 0; reg < 4; ++reg)
        sc[reg] = 1.f / fmaxf(sqrtf(sq[reg]), 1e-12f);

    const int rowBase = r0 + m0 + (lane >> 4)*4;
    #pragma unroll
    for (int nt = 0; nt < 16; ++nt){
        const int col = nt*16 + (lane & 15);
        #pragma unroll
        for (int reg = 0; reg < 4; ++reg)
            HN[(size_t)(rowBase + reg)*DD + col] = f2bf(acc[nt][reg]*sc[reg]);
    }
}

// ---------- loss/acc reduction (bf16 HN) ----------
__global__ __launch_bounds__(256) void k_reduce(
    const float* __restrict__ z2, const unsigned short* __restrict__ HN,
    double* __restrict__ loss_part, long long* __restrict__ cnt_part)
{
    const int tid = threadIdx.x;
    const int wave = tid >> 6, lane = tid & 63;
    const int gw = blockIdx.x*4 + wave;
    double lacc = 0.0;
    int cacc = 0;
    for (int r = gw; r < NROW; r += RBLK*4){
        const int b = r / NN, n = r % NN;
        const int pb = (5*b + 3) & 7;                 // fixed bijection on batch
        const int qn = (n * 7919 + 1234) % NN;        // fixed bijection on nodes
        const float4 zv = *(const float4*)&z2[(size_t)r*DD + lane*4];
        const ushort4 u0 = *(const ushort4*)&HN[(size_t)r*DD + lane*4];
        const ushort4 u1 = *(const ushort4*)&HN[(size_t)(pb*NN + qn)*DD + lane*4];
        float pz = zv.x*zv.x + zv.y*zv.y + zv.z*zv.z + zv.w*zv.w;
        float pr = zv.x*bf2f(u0.x) + zv.y*bf2f(u0.y) + zv.z*bf2f(u0.z) + zv.w*bf2f(u0.w);
        float pf = zv.x*bf2f(u1.x) + zv.y*bf2f(u1.y) + zv.z*bf2f(u1.z) + zv.w*bf2f(u1.w);
        #pragma unroll
        for (int o = 32; o > 0; o >>= 1){
            pz += __shfl_xor(pz, o, 64);
            pr += __shfl_xor(pr, o, 64);
            pf += __shfl_xor(pf, o, 64);
        }
        if (lane == 0){
            const float dn = fmaxf(sqrtf(pz), 1e-12f);
            const float x = pr / dn, y = pf / dn;
            const float lr = fmaxf(x, 0.f) - x + log1pf(expf(-fabsf(x)));  // lbl=1
            const float lf = fmaxf(y, 0.f)     + log1pf(expf(-fabsf(y)));  // lbl=0
            lacc += (double)(lr + lf);
            cacc += (x > 0.f ? 1 : 0) + (y > 0.f ? 0 : 1);
        }
    }
    __shared__ double sl[4];
    __shared__ int scn[4];
    if (lane == 0){ sl[wave] = lacc; scn[wave] = cacc; }
    __syncthreads();
    if (tid == 0){
        loss_part[blockIdx.x] = sl[0]+sl[1]+sl[2]+sl[3];
        cnt_part[blockIdx.x]  = (long long)scn[0] + scn[1] + scn[2] + scn[3];
    }
}

__global__ void k_final(const double* __restrict__ loss_part,
                        const long long* __restrict__ cnt_part,
                        float* __restrict__ out){
    __shared__ double sl[256];
    __shared__ long long sc[256];
    double l = 0.0; long long c = 0;
    for (int i = threadIdx.x; i < RBLK; i += 256){ l += loss_part[i]; c += cnt_part[i]; }
    sl[threadIdx.x] = l; sc[threadIdx.x] = c;
    __syncthreads();
    for (int s = 128; s > 0; s >>= 1){
        if (threadIdx.x < s){
            sl[threadIdx.x] += sl[threadIdx.x + s];
            sc[threadIdx.x] += sc[threadIdx.x + s];
        }
        __syncthreads();
    }
    if (threadIdx.x == 0){
        const double denom = 2.0 * BSZ * NN;   // 160000
        out[0] = (float)(sl[0] / denom);
        out[1] = (float)((double)sc[0] / denom);
    }
}

// ---------- host ----------
extern "C" void kernel_launch(void* const* d_in, const int* in_sizes, int n_in,
                              void* d_out, int out_size, void* d_ws, size_t ws_size,
                              hipStream_t stream)
{
    (void)in_sizes; (void)n_in; (void)out_size;
    const float* z1    = (const float*)d_in[0];
    const float* z2    = (const float*)d_in[1];
    const int*   ei    = (const int*)d_in[2];
    const float* ew    = (const float*)d_in[3];
    const float* sa_w  = (const float*)d_in[4];
    const float* sa_b  = (const float*)d_in[5];
    const float* lin_w = (const float*)d_in[6];
    const float* lin_b = (const float*)d_in[7];
    float* out = (float*)d_out;

    char* ws = (char*)d_ws;
    size_t off = 0;
    auto take = [&](size_t bytes) -> char* {
        char* p = ws + off;
        off = (off + bytes + 255) & ~(size_t)255;
        return p;
    };
    int*            flag      = (int*)take(4);
    int*            fill      = (int*)take((size_t)NN*4);
    int*            bc        = (int*)take((size_t)NN*BCAP*4);
    float*          bw        = (float*)take((size_t)NN*BCAP*4);
    int*            be        = (int*)take((size_t)NN*BCAP*4);
    int*            nbr_idx   = (int*)take((size_t)NN*KK*4);
    int*            nbr_cnt   = (int*)take((size_t)NN*4);
    unsigned short* Bpack     = (unsigned short*)take((size_t)16*8*64*8*2);
    float*          S         = (float*)take((size_t)NROW*4);
    float*          attw      = (float*)take((size_t)NROW*KK*4);
    double*         loss_part = (double*)take((size_t)RBLK*8);
    long long*      cnt_part  = (long long*)take((size_t)RBLK*8);
    unsigned short* HN        = (unsigned short*)take((size_t)NROW*DD*2);
    const size_t    need_base = off;
    unsigned short* z1b       = (unsigned short*)take((size_t)NROW*DD*2);
    const bool useB = (ws_size >= off);
    (void)need_base;

    k_zero<<<(NN+255)/256, 256, 0, stream>>>(fill);
    k_detect<<<1, 64, 0, stream>>>(ei, flag);
    k_fill<<<(EE+255)/256, 256, 0, stream>>>(ei, ew, flag, fill, bc, bw, be);
    k_top5<<<(NN+3)/4, 256, 0, stream>>>(fill, bc, bw, be, nbr_idx, nbr_cnt);
    k_pack<<<32, 256, 0, stream>>>(lin_w, Bpack);
    if (useB) k_prep<true ><<<1250, 256, 0, stream>>>(z1, sa_w, sa_b, z1b, S);
    else      k_prep<false><<<1250, 256, 0, stream>>>(z1, sa_w, sa_b, z1b, S);
    k_attn<<<(NROW+255)/256, 256, 0, stream>>>(nbr_idx, nbr_cnt, S, attw);
    if (useB) k_fused<true ><<<NROW/64, 256, 0, stream>>>(z1, z1b, nbr_idx, attw, Bpack, lin_b, HN);
    else      k_fused<false><<<NROW/64, 256, 0, stream>>>(z1, z1b, nbr_idx, attw, Bpack, lin_b, HN);
    k_reduce<<<RBLK, 256, 0, stream>>>(z2, HN, loss_part, cnt_part);
    k_final<<<1, 256, 0, stream>>>(loss_part, cnt_part, out);
}